// Round 10
// baseline (176.634 us; speedup 1.0000x reference)
//
#include <hip/hip_runtime.h>
#include <hip/hip_fp16.h>
#include <math.h>

#define N_NODES 50000
#define N_EDGES 800000
#define N_FEAT 100
#define N_CLASSES 40
#define N_SLICES 8
#define SLICE_NODES 6250           // N_NODES / N_SLICES exactly
#define FILL_CHUNKS 256
#define FILL_EDGES_PER_CHUNK 3125  // N_EDGES / FILL_CHUNKS exactly
#define SCAN_BLK 256
#define N_SCAN_BLKS ((N_NODES + SCAN_BLK - 1) / SCAN_BLK)  // 196

// ---------------- zero deg ----------------

__global__ void k_zero(uint4* __restrict__ p, int n4) {
    int i = blockIdx.x * blockDim.x + threadIdx.x;
    if (i < n4) p[i] = make_uint4(0u, 0u, 0u, 0u);
}

// ---------------- convert to packed u32 + degree count (dtype decided per wave) ----------------

__global__ void k_convert(const void* __restrict__ ei,
                          unsigned int* __restrict__ epack, int* __restrict__ deg) {
    int e = blockIdx.x * blockDim.x + threadIdx.x;
    long long v = ((const long long*)ei)[e];
    bool bad = (v < 0 || v >= N_NODES);
    bool is32 = (__ballot(bad) != 0ull);  // wave-uniform
    unsigned int r, c;
    if (is32) {
        const unsigned int* p = (const unsigned int*)ei;
        r = p[e];
        c = p[N_EDGES + e];
    } else {
        r = (unsigned int)v;
        c = (unsigned int)((const long long*)ei)[N_EDGES + e];
    }
    epack[e] = r | (c << 16);
    atomicAdd(&deg[c], 1);  // fire-and-forget
}

// ---------------- 3-kernel exclusive scan: deg -> offs (+ dinv / dinv16 fused) ----------------

__global__ void k_scan1(const int* __restrict__ deg, int* __restrict__ offs,
                        int* __restrict__ sums, float* __restrict__ dinv,
                        unsigned short* __restrict__ dinv16) {
    __shared__ int s[SCAN_BLK];
    int i = blockIdx.x * SCAN_BLK + threadIdx.x;
    int v = (i < N_NODES) ? deg[i] : 0;
    if (i < N_NODES) {
        float d = rsqrtf((float)v + 1.0f);  // +1 self-loop
        dinv[i] = d;
        dinv16[i] = __half_as_ushort(__float2half_rn(d));
    }
    s[threadIdx.x] = v;
    __syncthreads();
    for (int off = 1; off < SCAN_BLK; off <<= 1) {
        int t = (threadIdx.x >= off) ? s[threadIdx.x - off] : 0;
        __syncthreads();
        s[threadIdx.x] += t;
        __syncthreads();
    }
    if (i < N_NODES) offs[i] = s[threadIdx.x] - v;  // exclusive
    if (threadIdx.x == SCAN_BLK - 1) sums[blockIdx.x] = s[SCAN_BLK - 1];
}

__global__ void k_scan2(int* __restrict__ sums) {
    __shared__ int s[SCAN_BLK];
    int v = (threadIdx.x < N_SCAN_BLKS) ? sums[threadIdx.x] : 0;
    s[threadIdx.x] = v;
    __syncthreads();
    for (int off = 1; off < SCAN_BLK; off <<= 1) {
        int t = (threadIdx.x >= off) ? s[threadIdx.x - off] : 0;
        __syncthreads();
        s[threadIdx.x] += t;
        __syncthreads();
    }
    if (threadIdx.x < N_SCAN_BLKS) sums[threadIdx.x] = s[threadIdx.x] - v;  // exclusive
}

__global__ void k_scan3(int* __restrict__ offs, const int* __restrict__ sums,
                        int* __restrict__ cursor) {
    int i = blockIdx.x * SCAN_BLK + threadIdx.x;
    if (i < N_NODES) {
        int o = offs[i] + sums[blockIdx.x];
        offs[i] = o;
        cursor[i] = o;
    }
    if (i == 0) offs[N_NODES] = N_EDGES;
}

// ---------------- XCD-sliced CSR fill: 4B entry = r | f16(dinv[r])<<16 ----------------

__global__ void k_fill(const unsigned int* __restrict__ epack,
                       const unsigned short* __restrict__ dinv16,
                       int* __restrict__ cursor, unsigned int* __restrict__ csr) {
    int slice = blockIdx.x & (N_SLICES - 1);
    int chunk = blockIdx.x >> 3;
    unsigned int lo = slice * SLICE_NODES;
    int e0 = chunk * FILL_EDGES_PER_CHUNK;
    int e1 = e0 + FILL_EDGES_PER_CHUNK;
    for (int e = e0 + threadIdx.x; e < e1; e += blockDim.x) {
        unsigned int p = epack[e];
        unsigned int c = p >> 16;
        if (c - lo < SLICE_NODES) {  // c in [lo, lo+SLICE_NODES)
            unsigned int r = p & 0xffffu;
            int pos = atomicAdd(&cursor[c], 1);
            csr[pos] = r | ((unsigned int)dinv16[r] << 16);
        }
    }
}

// ---------------- linear: y0 = x @ W, fp16 out (bias deferred) ----------------

__global__ void k_linear(const float* __restrict__ h, const float* __restrict__ W,
                         __half* __restrict__ y) {
    __shared__ float4 Ws[N_CLASSES / 4][N_FEAT];  // 16 KB
    for (int i = threadIdx.x; i < N_FEAT * (N_CLASSES / 4); i += blockDim.x) {
        int k = i / (N_CLASSES / 4), c4 = i - k * (N_CLASSES / 4);
        Ws[c4][k] = ((const float4*)W)[i];
    }
    __syncthreads();
    int idx = blockIdx.x * blockDim.x + threadIdx.x;
    if (idx >= N_NODES * (N_CLASSES / 4)) return;
    int n = idx / (N_CLASSES / 4);
    int c4 = idx - n * (N_CLASSES / 4);
    const float* hr = h + n * N_FEAT;
    float4 s = {0.f, 0.f, 0.f, 0.f};
#pragma unroll
    for (int k = 0; k < N_FEAT; ++k) {
        float hv = hr[k];
        float4 w = Ws[c4][k];
        s.x += hv * w.x; s.y += hv * w.y; s.z += hv * w.z; s.w += hv * w.w;
    }
    __half2* yo = (__half2*)(y + (size_t)idx * 4);
    yo[0] = __floats2half2_rn(s.x, s.y);
    yo[1] = __floats2half2_rn(s.z, s.w);
}

// ---------------- pull-gather hop, 4B csr entries, 16-deep MLP ----------------
// dst[c] = dinv_c * ( dinv_c * x_c + sum_r f16(dinv_r) * x_r )
// one wave per node (lanes 0..39 = classes), 4 nodes per 256-thread block

#define EDGE_W(q) __half2float(__ushort_as_half((unsigned short)((q) >> 16)))
#define EDGE_R(q) ((q) & 0xffffu)

template <bool LSM, typename DstT>
__global__ void k_gather(const int* __restrict__ offs, const unsigned int* __restrict__ csr,
                         const __half* __restrict__ src, const float* __restrict__ dinv,
                         DstT* __restrict__ dst, const float* __restrict__ bias) {
    int wave = threadIdx.x >> 6;
    int lane = threadIdx.x & 63;
    int n = blockIdx.x * 4 + wave;
    if (n >= N_NODES) return;
    int s = offs[n], e = offs[n + 1];
    bool act = (lane < N_CLASSES);
    float dc = dinv[n];
    const __half* sl = src + lane;  // per-lane base; addr = sl + 40*r
    float acc0 = 0.0f, acc1 = 0.0f, acc2 = 0.0f, acc3 = 0.0f;
    if (act) acc0 = dc * __half2float(sl[(size_t)n * N_CLASSES]);  // self term (dc applied again at end)
    int i = s;
    // peel to 4-entry (16B) alignment
    for (; (i & 3) && i < e; ++i) {
        unsigned int q = csr[i];
        if (act) acc1 += EDGE_W(q) * __half2float(sl[(size_t)EDGE_R(q) * N_CLASSES]);
    }
    for (; i + 15 < e; i += 16) {
        uint4 q0 = *(const uint4*)(csr + i);
        uint4 q1 = *(const uint4*)(csr + i + 4);
        uint4 q2 = *(const uint4*)(csr + i + 8);
        uint4 q3 = *(const uint4*)(csr + i + 12);
        if (act) {
            float v0  = __half2float(sl[(size_t)EDGE_R(q0.x) * N_CLASSES]);
            float v1  = __half2float(sl[(size_t)EDGE_R(q0.y) * N_CLASSES]);
            float v2  = __half2float(sl[(size_t)EDGE_R(q0.z) * N_CLASSES]);
            float v3  = __half2float(sl[(size_t)EDGE_R(q0.w) * N_CLASSES]);
            float v4  = __half2float(sl[(size_t)EDGE_R(q1.x) * N_CLASSES]);
            float v5  = __half2float(sl[(size_t)EDGE_R(q1.y) * N_CLASSES]);
            float v6  = __half2float(sl[(size_t)EDGE_R(q1.z) * N_CLASSES]);
            float v7  = __half2float(sl[(size_t)EDGE_R(q1.w) * N_CLASSES]);
            float v8  = __half2float(sl[(size_t)EDGE_R(q2.x) * N_CLASSES]);
            float v9  = __half2float(sl[(size_t)EDGE_R(q2.y) * N_CLASSES]);
            float v10 = __half2float(sl[(size_t)EDGE_R(q2.z) * N_CLASSES]);
            float v11 = __half2float(sl[(size_t)EDGE_R(q2.w) * N_CLASSES]);
            float v12 = __half2float(sl[(size_t)EDGE_R(q3.x) * N_CLASSES]);
            float v13 = __half2float(sl[(size_t)EDGE_R(q3.y) * N_CLASSES]);
            float v14 = __half2float(sl[(size_t)EDGE_R(q3.z) * N_CLASSES]);
            float v15 = __half2float(sl[(size_t)EDGE_R(q3.w) * N_CLASSES]);
            acc0 += EDGE_W(q0.x) * v0;  acc1 += EDGE_W(q0.y) * v1;
            acc2 += EDGE_W(q0.z) * v2;  acc3 += EDGE_W(q0.w) * v3;
            acc0 += EDGE_W(q1.x) * v4;  acc1 += EDGE_W(q1.y) * v5;
            acc2 += EDGE_W(q1.z) * v6;  acc3 += EDGE_W(q1.w) * v7;
            acc0 += EDGE_W(q2.x) * v8;  acc1 += EDGE_W(q2.y) * v9;
            acc2 += EDGE_W(q2.z) * v10; acc3 += EDGE_W(q2.w) * v11;
            acc0 += EDGE_W(q3.x) * v12; acc1 += EDGE_W(q3.y) * v13;
            acc2 += EDGE_W(q3.z) * v14; acc3 += EDGE_W(q3.w) * v15;
        }
    }
    for (; i + 3 < e; i += 4) {
        uint4 q0 = *(const uint4*)(csr + i);
        if (act) {
            float v0 = __half2float(sl[(size_t)EDGE_R(q0.x) * N_CLASSES]);
            float v1 = __half2float(sl[(size_t)EDGE_R(q0.y) * N_CLASSES]);
            float v2 = __half2float(sl[(size_t)EDGE_R(q0.z) * N_CLASSES]);
            float v3 = __half2float(sl[(size_t)EDGE_R(q0.w) * N_CLASSES]);
            acc0 += EDGE_W(q0.x) * v0; acc1 += EDGE_W(q0.y) * v1;
            acc2 += EDGE_W(q0.z) * v2; acc3 += EDGE_W(q0.w) * v3;
        }
    }
    for (; i < e; ++i) {
        unsigned int q = csr[i];
        if (act) acc2 += EDGE_W(q) * __half2float(sl[(size_t)EDGE_R(q) * N_CLASSES]);
    }
    float acc = dc * ((acc0 + acc1) + (acc2 + acc3));
    if (!LSM) {
        if (act) {
            if constexpr (sizeof(DstT) == 2)
                dst[(size_t)n * N_CLASSES + lane] = __float2half_rn(acc);
            else
                dst[(size_t)n * N_CLASSES + lane] = acc;
        }
    } else {
        float v = act ? acc + bias[lane] : -INFINITY;
        float m = v;
#pragma unroll
        for (int off = 32; off; off >>= 1) m = fmaxf(m, __shfl_xor(m, off));
        float ex = act ? __expf(v - m) : 0.0f;
        float ssum = ex;
#pragma unroll
        for (int off = 32; off; off >>= 1) ssum += __shfl_xor(ssum, off);
        float ls = logf(ssum);
        if (act) dst[(size_t)n * N_CLASSES + lane] = (DstT)(v - m - ls);
    }
}

// ---------------- launch ----------------

extern "C" void kernel_launch(void* const* d_in, const int* in_sizes, int n_in,
                              void* d_out, int out_size, void* d_ws, size_t ws_size,
                              hipStream_t stream) {
    const float* x = (const float*)d_in[0];
    const void* ei = d_in[1];                // [2, E], int32 or int64 (wave-local detect)
    const float* W = (const float*)d_in[2];  // [F, C]
    const float* b = (const float*)d_in[3];  // [C]
    float* z = (float*)d_out;                // [N, C]

    // workspace layout (256B-aligned chunks)
    char* ws = (char*)d_ws;
    size_t o = 0;
    auto alloc = [&](size_t bytes) { char* p = ws + o; o += (bytes + 255) & ~(size_t)255; return p; };
    int*            deg    = (int*)alloc(N_NODES * 4);  // 50000 -> 12500 uint4
    unsigned int*   epack  = (unsigned int*)alloc((size_t)N_EDGES * 4);
    float*          dinv   = (float*)alloc(N_NODES * 4);
    unsigned short* dinv16 = (unsigned short*)alloc(N_NODES * 2);
    int*            offs   = (int*)alloc((N_NODES + 1) * 4);
    int*            cursor = (int*)alloc(N_NODES * 4);
    int*            sums   = (int*)alloc(SCAN_BLK * 4);
    unsigned int*   csr    = (unsigned int*)alloc((size_t)N_EDGES * 4);
    __half*         y0     = (__half*)alloc((size_t)N_NODES * N_CLASSES * 2);
    __half*         h1     = (__half*)alloc((size_t)N_NODES * N_CLASSES * 2);

    const int T = 256;
    auto blocks = [](long long total, int t) { return (int)((total + t - 1) / t); };

    // zero deg
    k_zero<<<blocks(12500, T), T, 0, stream>>>((uint4*)deg, 12500);

    // convert (dtype ballot + degree count fused)
    k_convert<<<blocks(N_EDGES, T), T, 0, stream>>>(ei, epack, deg);

    // 3-kernel exclusive scan -> offs, cursor (dinv/dinv16 fused into scan1)
    k_scan1<<<N_SCAN_BLKS, SCAN_BLK, 0, stream>>>(deg, offs, sums, dinv, dinv16);
    k_scan2<<<1, SCAN_BLK, 0, stream>>>(sums);
    k_scan3<<<N_SCAN_BLKS, SCAN_BLK, 0, stream>>>(offs, sums, cursor);

    // XCD-sliced CSR fill (4B entries)
    k_fill<<<FILL_CHUNKS * N_SLICES, T, 0, stream>>>(epack, dinv16, cursor, csr);

    // y0 = x @ W (fp16 out; W commutes with propagation; both hops F=40)
    k_linear<<<blocks((long long)N_NODES * (N_CLASSES / 4), T), T, 0, stream>>>(x, W, y0);

    // hop 1: h1 = A_hat @ y0  (fp16 -> fp16)
    k_gather<false, __half><<<(N_NODES + 3) / 4, T, 0, stream>>>(offs, csr, y0, dinv, h1, b);
    // hop 2 fused with bias + log_softmax  (fp16 -> fp32 out)
    k_gather<true, float><<<(N_NODES + 3) / 4, T, 0, stream>>>(offs, csr, h1, dinv, z, b);
}

// Round 11
// 170.401 us; speedup vs baseline: 1.0366x; 1.0366x over previous
//
#include <hip/hip_runtime.h>
#include <hip/hip_fp16.h>
#include <math.h>

#define N_NODES 50000
#define N_EDGES 800000
#define N_FEAT 100
#define N_CLASSES 40
#define N_SLICES 8
#define SLICE_NODES 6250           // N_NODES / N_SLICES exactly
#define FILL_CHUNKS 256
#define FILL_EDGES_PER_CHUNK 3125  // N_EDGES / FILL_CHUNKS exactly
#define SCAN_BLK 256
#define N_SCAN_BLKS ((N_NODES + SCAN_BLK - 1) / SCAN_BLK)  // 196

// ---------------- zero deg ----------------

__global__ void k_zero(uint4* __restrict__ p, int n4) {
    int i = blockIdx.x * blockDim.x + threadIdx.x;
    if (i < n4) p[i] = make_uint4(0u, 0u, 0u, 0u);
}

// ---------------- convert to packed u32 + degree count (dtype decided per wave) ----------------

__global__ void k_convert(const void* __restrict__ ei,
                          unsigned int* __restrict__ epack, int* __restrict__ deg) {
    int e = blockIdx.x * blockDim.x + threadIdx.x;
    long long v = ((const long long*)ei)[e];
    bool bad = (v < 0 || v >= N_NODES);
    bool is32 = (__ballot(bad) != 0ull);  // wave-uniform
    unsigned int r, c;
    if (is32) {
        const unsigned int* p = (const unsigned int*)ei;
        r = p[e];
        c = p[N_EDGES + e];
    } else {
        r = (unsigned int)v;
        c = (unsigned int)((const long long*)ei)[N_EDGES + e];
    }
    epack[e] = r | (c << 16);
    atomicAdd(&deg[c], 1);  // fire-and-forget
}

// ---------------- 2-kernel exclusive scan: deg -> offs (+ dinv / dinv16 fused) ----------------

__global__ void k_scan1(const int* __restrict__ deg, int* __restrict__ offs,
                        int* __restrict__ sums, float* __restrict__ dinv,
                        unsigned short* __restrict__ dinv16) {
    __shared__ int s[SCAN_BLK];
    int i = blockIdx.x * SCAN_BLK + threadIdx.x;
    int v = (i < N_NODES) ? deg[i] : 0;
    if (i < N_NODES) {
        float d = rsqrtf((float)v + 1.0f);  // +1 self-loop
        dinv[i] = d;
        dinv16[i] = __half_as_ushort(__float2half_rn(d));
    }
    s[threadIdx.x] = v;
    __syncthreads();
    for (int off = 1; off < SCAN_BLK; off <<= 1) {
        int t = (threadIdx.x >= off) ? s[threadIdx.x - off] : 0;
        __syncthreads();
        s[threadIdx.x] += t;
        __syncthreads();
    }
    if (i < N_NODES) offs[i] = s[threadIdx.x] - v;  // exclusive within block
    if (threadIdx.x == SCAN_BLK - 1) sums[blockIdx.x] = s[SCAN_BLK - 1];
}

// scan2 folded in: every block redundantly scans the 196 block sums in LDS
__global__ void k_scan3(int* __restrict__ offs, const int* __restrict__ sums,
                        int* __restrict__ cursor, unsigned int* __restrict__ csr) {
    __shared__ int sc[SCAN_BLK];
    __shared__ int orig[SCAN_BLK];
    int t = threadIdx.x;
    int v = (t < N_SCAN_BLKS) ? sums[t] : 0;
    sc[t] = v; orig[t] = v;
    __syncthreads();
    for (int off = 1; off < SCAN_BLK; off <<= 1) {
        int u = (t >= off) ? sc[t - off] : 0;
        __syncthreads();
        sc[t] += u;
        __syncthreads();
    }
    int base = sc[blockIdx.x] - orig[blockIdx.x];  // exclusive prefix of this block
    int i = blockIdx.x * SCAN_BLK + t;
    if (i < N_NODES) {
        int o = offs[i] + base;
        offs[i] = o;
        cursor[i] = o;
    }
    if (i == 0) offs[N_NODES] = N_EDGES;
    if (blockIdx.x == 0 && t < 16) csr[N_EDGES + t] = 0u;  // pad for full-width gather groups
}

// ---------------- XCD-sliced CSR fill: 4B entry = r | f16(dinv[r])<<16 ----------------

__global__ void k_fill(const unsigned int* __restrict__ epack,
                       const unsigned short* __restrict__ dinv16,
                       int* __restrict__ cursor, unsigned int* __restrict__ csr) {
    int slice = blockIdx.x & (N_SLICES - 1);
    int chunk = blockIdx.x >> 3;
    unsigned int lo = slice * SLICE_NODES;
    int e0 = chunk * FILL_EDGES_PER_CHUNK;
    int e1 = e0 + FILL_EDGES_PER_CHUNK;
    for (int e = e0 + threadIdx.x; e < e1; e += blockDim.x) {
        unsigned int p = epack[e];
        unsigned int c = p >> 16;
        if (c - lo < SLICE_NODES) {  // c in [lo, lo+SLICE_NODES)
            unsigned int r = p & 0xffffu;
            int pos = atomicAdd(&cursor[c], 1);
            csr[pos] = r | ((unsigned int)dinv16[r] << 16);
        }
    }
}

// ---------------- linear: y0 = x @ W, fp16 out (bias deferred) ----------------

__global__ void k_linear(const float* __restrict__ h, const float* __restrict__ W,
                         __half* __restrict__ y) {
    __shared__ float4 Ws[N_CLASSES / 4][N_FEAT];  // 16 KB
    for (int i = threadIdx.x; i < N_FEAT * (N_CLASSES / 4); i += blockDim.x) {
        int k = i / (N_CLASSES / 4), c4 = i - k * (N_CLASSES / 4);
        Ws[c4][k] = ((const float4*)W)[i];
    }
    __syncthreads();
    int idx = blockIdx.x * blockDim.x + threadIdx.x;
    if (idx >= N_NODES * (N_CLASSES / 4)) return;
    int n = idx / (N_CLASSES / 4);
    int c4 = idx - n * (N_CLASSES / 4);
    const float* hr = h + n * N_FEAT;
    float4 s = {0.f, 0.f, 0.f, 0.f};
#pragma unroll
    for (int k = 0; k < N_FEAT; ++k) {
        float hv = hr[k];
        float4 w = Ws[c4][k];
        s.x += hv * w.x; s.y += hv * w.y; s.z += hv * w.z; s.w += hv * w.w;
    }
    __half2* yo = (__half2*)(y + (size_t)idx * 4);
    yo[0] = __floats2half2_rn(s.x, s.y);
    yo[1] = __floats2half2_rn(s.z, s.w);
}

// ---------------- pull-gather hop: branchless full-width 16-edge groups ----------------
// dst[c] = dinv_c * ( dinv_c * x_c + sum_r f16(dinv_r) * x_r )
// Groups start at (s & ~15): every load is a full 64B-aligned line; slots outside
// [s,e) get weight 0 (their indices are valid memory -> finite values * 0).

#define GPROC(Q, K, ACC)                                                         \
    {                                                                            \
        unsigned int q_ = (Q);                                                   \
        int idx_ = base + (K);                                                   \
        float vv_ = __half2float(sl[(size_t)(q_ & 0xffffu) * N_CLASSES]);        \
        unsigned int wb_ = (idx_ >= s && idx_ < e) ? (q_ >> 16) : 0u;            \
        ACC += __half2float(__ushort_as_half((unsigned short)wb_)) * vv_;        \
    }

template <bool LSM, typename DstT>
__global__ void k_gather(const int* __restrict__ offs, const unsigned int* __restrict__ csr,
                         const __half* __restrict__ src, const float* __restrict__ dinv,
                         DstT* __restrict__ dst, const float* __restrict__ bias) {
    int wave = threadIdx.x >> 6;
    int lane = threadIdx.x & 63;
    int n = blockIdx.x * 4 + wave;
    if (n >= N_NODES) return;
    int s = offs[n], e = offs[n + 1];
    bool act = (lane < N_CLASSES);
    float dc = dinv[n];
    const __half* sl = src + lane;  // per-lane base; addr = sl + 40*r
    float acc0 = 0.0f, acc1 = 0.0f, acc2 = 0.0f, acc3 = 0.0f;
    if (act) acc0 = dc * __half2float(sl[(size_t)n * N_CLASSES]);  // self term
    for (int base = (s & ~15); base < e; base += 16) {
        uint4 q0 = *(const uint4*)(csr + base);
        uint4 q1 = *(const uint4*)(csr + base + 4);
        uint4 q2 = *(const uint4*)(csr + base + 8);
        uint4 q3 = *(const uint4*)(csr + base + 12);
        if (act) {
            GPROC(q0.x,  0, acc0) GPROC(q0.y,  1, acc1) GPROC(q0.z,  2, acc2) GPROC(q0.w,  3, acc3)
            GPROC(q1.x,  4, acc0) GPROC(q1.y,  5, acc1) GPROC(q1.z,  6, acc2) GPROC(q1.w,  7, acc3)
            GPROC(q2.x,  8, acc0) GPROC(q2.y,  9, acc1) GPROC(q2.z, 10, acc2) GPROC(q2.w, 11, acc3)
            GPROC(q3.x, 12, acc0) GPROC(q3.y, 13, acc1) GPROC(q3.z, 14, acc2) GPROC(q3.w, 15, acc3)
        }
    }
    float acc = dc * ((acc0 + acc1) + (acc2 + acc3));
    if (!LSM) {
        if (act) {
            if constexpr (sizeof(DstT) == 2)
                dst[(size_t)n * N_CLASSES + lane] = __float2half_rn(acc);
            else
                dst[(size_t)n * N_CLASSES + lane] = acc;
        }
    } else {
        float v = act ? acc + bias[lane] : -INFINITY;
        float m = v;
#pragma unroll
        for (int off = 32; off; off >>= 1) m = fmaxf(m, __shfl_xor(m, off));
        float ex = act ? __expf(v - m) : 0.0f;
        float ssum = ex;
#pragma unroll
        for (int off = 32; off; off >>= 1) ssum += __shfl_xor(ssum, off);
        float ls = logf(ssum);
        if (act) dst[(size_t)n * N_CLASSES + lane] = (DstT)(v - m - ls);
    }
}

// ---------------- launch ----------------

extern "C" void kernel_launch(void* const* d_in, const int* in_sizes, int n_in,
                              void* d_out, int out_size, void* d_ws, size_t ws_size,
                              hipStream_t stream) {
    const float* x = (const float*)d_in[0];
    const void* ei = d_in[1];                // [2, E], int32 or int64 (wave-local detect)
    const float* W = (const float*)d_in[2];  // [F, C]
    const float* b = (const float*)d_in[3];  // [C]
    float* z = (float*)d_out;                // [N, C]

    // workspace layout (256B-aligned chunks)
    char* ws = (char*)d_ws;
    size_t o = 0;
    auto alloc = [&](size_t bytes) { char* p = ws + o; o += (bytes + 255) & ~(size_t)255; return p; };
    int*            deg    = (int*)alloc(N_NODES * 4);  // 50000 -> 12500 uint4
    unsigned int*   epack  = (unsigned int*)alloc((size_t)N_EDGES * 4);
    float*          dinv   = (float*)alloc(N_NODES * 4);
    unsigned short* dinv16 = (unsigned short*)alloc(N_NODES * 2);
    int*            offs   = (int*)alloc((N_NODES + 1) * 4);
    int*            cursor = (int*)alloc(N_NODES * 4);
    int*            sums   = (int*)alloc(SCAN_BLK * 4);
    unsigned int*   csr    = (unsigned int*)alloc((size_t)(N_EDGES + 16) * 4);
    __half*         y0     = (__half*)alloc((size_t)N_NODES * N_CLASSES * 2);
    __half*         h1     = (__half*)alloc((size_t)N_NODES * N_CLASSES * 2);

    const int T = 256;
    auto blocks = [](long long total, int t) { return (int)((total + t - 1) / t); };

    // zero deg
    k_zero<<<blocks(12500, T), T, 0, stream>>>((uint4*)deg, 12500);

    // convert (dtype ballot + degree count fused)
    k_convert<<<blocks(N_EDGES, T), T, 0, stream>>>(ei, epack, deg);

    // 2-kernel exclusive scan -> offs, cursor (dinv/dinv16 fused; scan2 folded into scan3)
    k_scan1<<<N_SCAN_BLKS, SCAN_BLK, 0, stream>>>(deg, offs, sums, dinv, dinv16);
    k_scan3<<<N_SCAN_BLKS, SCAN_BLK, 0, stream>>>(offs, sums, cursor, csr);

    // XCD-sliced CSR fill (4B entries)
    k_fill<<<FILL_CHUNKS * N_SLICES, T, 0, stream>>>(epack, dinv16, cursor, csr);

    // y0 = x @ W (fp16 out; W commutes with propagation; both hops F=40)
    k_linear<<<blocks((long long)N_NODES * (N_CLASSES / 4), T), T, 0, stream>>>(x, W, y0);

    // hop 1: h1 = A_hat @ y0  (fp16 -> fp16)
    k_gather<false, __half><<<(N_NODES + 3) / 4, T, 0, stream>>>(offs, csr, y0, dinv, h1, b);
    // hop 2 fused with bias + log_softmax  (fp16 -> fp32 out)
    k_gather<true, float><<<(N_NODES + 3) / 4, T, 0, stream>>>(offs, csr, h1, dinv, z, b);
}

// Round 12
// 169.903 us; speedup vs baseline: 1.0396x; 1.0029x over previous
//
#include <hip/hip_runtime.h>
#include <hip/hip_fp16.h>
#include <hip/hip_fp8.h>
#include <math.h>

#define N_NODES 50000
#define N_EDGES 800000
#define N_FEAT 100
#define N_CLASSES 40
#define ROWB 64                    // fp8 row stride (bytes): 40 data + 24 pad = 1 cache line
#define N_SLICES 8
#define SLICE_NODES 6250           // N_NODES / N_SLICES exactly
#define FILL_CHUNKS 256
#define FILL_BLOCKS (FILL_CHUNKS * N_SLICES)  // 2048
#define FILL_EDGES_PER_CHUNK 3125  // N_EDGES / FILL_CHUNKS exactly
#define LIN_ITEMS (N_NODES * (N_CLASSES / 4))          // 500000
#define LIN_BLOCKS ((LIN_ITEMS + 255) / 256)           // 1954
#define SCAN_BLK 256
#define N_SCAN_BLKS ((N_NODES + SCAN_BLK - 1) / SCAN_BLK)  // 196

// ---------------- fp8 e4m3 helpers ----------------

__device__ __forceinline__ unsigned char f2q(float x) {
    __hip_fp8_e4m3 q(x);
    return (unsigned char)q.__x;
}
__device__ __forceinline__ float q2f(unsigned char b) {
    __hip_fp8_e4m3 q;
    q.__x = (__hip_fp8_storage_t)b;
    return (float)q;
}

// ---------------- zero deg ----------------

__global__ void k_zero(uint4* __restrict__ p, int n4) {
    int i = blockIdx.x * blockDim.x + threadIdx.x;
    if (i < n4) p[i] = make_uint4(0u, 0u, 0u, 0u);
}

// ---------------- convert to packed u32 + degree count (dtype decided per wave) ----------------

__global__ void k_convert(const void* __restrict__ ei,
                          unsigned int* __restrict__ epack, int* __restrict__ deg) {
    int e = blockIdx.x * blockDim.x + threadIdx.x;
    long long v = ((const long long*)ei)[e];
    bool bad = (v < 0 || v >= N_NODES);
    bool is32 = (__ballot(bad) != 0ull);  // wave-uniform
    unsigned int r, c;
    if (is32) {
        const unsigned int* p = (const unsigned int*)ei;
        r = p[e];
        c = p[N_EDGES + e];
    } else {
        r = (unsigned int)v;
        c = (unsigned int)((const long long*)ei)[N_EDGES + e];
    }
    epack[e] = r | (c << 16);
    atomicAdd(&deg[c], 1);  // fire-and-forget
}

// ---------------- 2-kernel exclusive scan: deg -> offs (+ dinv / dinv16 fused) ----------------

__global__ void k_scan1(const int* __restrict__ deg, int* __restrict__ offs,
                        int* __restrict__ sums, float* __restrict__ dinv,
                        unsigned short* __restrict__ dinv16) {
    __shared__ int s[SCAN_BLK];
    int i = blockIdx.x * SCAN_BLK + threadIdx.x;
    int v = (i < N_NODES) ? deg[i] : 0;
    if (i < N_NODES) {
        float d = rsqrtf((float)v + 1.0f);  // +1 self-loop
        dinv[i] = d;
        dinv16[i] = __half_as_ushort(__float2half_rn(d));
    }
    s[threadIdx.x] = v;
    __syncthreads();
    for (int off = 1; off < SCAN_BLK; off <<= 1) {
        int t = (threadIdx.x >= off) ? s[threadIdx.x - off] : 0;
        __syncthreads();
        s[threadIdx.x] += t;
        __syncthreads();
    }
    if (i < N_NODES) offs[i] = s[threadIdx.x] - v;  // exclusive within block
    if (threadIdx.x == SCAN_BLK - 1) sums[blockIdx.x] = s[SCAN_BLK - 1];
}

// scan2 folded in: every block redundantly scans the 196 block sums in LDS
__global__ void k_scan3(int* __restrict__ offs, const int* __restrict__ sums,
                        int* __restrict__ cursor, unsigned int* __restrict__ csr) {
    __shared__ int sc[SCAN_BLK];
    __shared__ int orig[SCAN_BLK];
    int t = threadIdx.x;
    int v = (t < N_SCAN_BLKS) ? sums[t] : 0;
    sc[t] = v; orig[t] = v;
    __syncthreads();
    for (int off = 1; off < SCAN_BLK; off <<= 1) {
        int u = (t >= off) ? sc[t - off] : 0;
        __syncthreads();
        sc[t] += u;
        __syncthreads();
    }
    int base = sc[blockIdx.x] - orig[blockIdx.x];  // exclusive prefix of this block
    int i = blockIdx.x * SCAN_BLK + t;
    if (i < N_NODES) {
        int o = offs[i] + base;
        offs[i] = o;
        cursor[i] = o;
    }
    if (i == 0) offs[N_NODES] = N_EDGES;
    if (blockIdx.x == 0 && t < 16) csr[N_EDGES + t] = 0u;  // pad for full-width gather groups
}

// ---------------- fused: XCD-sliced CSR fill (blocks 0..2047) + linear y0q = fp8(x @ W) ----------------

__global__ void k_fill_linear(const unsigned int* __restrict__ epack,
                              const unsigned short* __restrict__ dinv16,
                              int* __restrict__ cursor, unsigned int* __restrict__ csr,
                              const float* __restrict__ x, const float* __restrict__ W,
                              unsigned char* __restrict__ y0q) {
    __shared__ float4 Ws[N_CLASSES / 4][N_FEAT];  // used by linear branch only (16 KB)
    if (blockIdx.x < FILL_BLOCKS) {
        int slice = blockIdx.x & (N_SLICES - 1);
        int chunk = blockIdx.x >> 3;
        unsigned int lo = slice * SLICE_NODES;
        int e0 = chunk * FILL_EDGES_PER_CHUNK;
        int e1 = e0 + FILL_EDGES_PER_CHUNK;
        for (int e = e0 + threadIdx.x; e < e1; e += blockDim.x) {
            unsigned int p = epack[e];
            unsigned int c = p >> 16;
            if (c - lo < SLICE_NODES) {  // c in [lo, lo+SLICE_NODES)
                unsigned int r = p & 0xffffu;
                int pos = atomicAdd(&cursor[c], 1);
                csr[pos] = r | ((unsigned int)dinv16[r] << 16);
            }
        }
    } else {
        for (int i = threadIdx.x; i < N_FEAT * (N_CLASSES / 4); i += blockDim.x) {
            int k = i / (N_CLASSES / 4), c4 = i - k * (N_CLASSES / 4);
            Ws[c4][k] = ((const float4*)W)[i];
        }
        __syncthreads();
        int idx = (blockIdx.x - FILL_BLOCKS) * blockDim.x + threadIdx.x;
        if (idx >= LIN_ITEMS) return;
        int n = idx / (N_CLASSES / 4);
        int c4 = idx - n * (N_CLASSES / 4);
        const float* hr = x + (size_t)n * N_FEAT;
        float4 s = {0.f, 0.f, 0.f, 0.f};
#pragma unroll
        for (int k = 0; k < N_FEAT; ++k) {
            float hv = hr[k];
            float4 w = Ws[c4][k];
            s.x += hv * w.x; s.y += hv * w.y; s.z += hv * w.z; s.w += hv * w.w;
        }
        uchar4 q = make_uchar4(f2q(s.x), f2q(s.y), f2q(s.z), f2q(s.w));
        *(uchar4*)(y0q + (size_t)n * ROWB + c4 * 4) = q;
    }
}

// ---------------- pull-gather hop over fp8 64B-row src: branchless 16-edge groups ----------------
// dst[c] = dinv_c * ( dinv_c * x_c + sum_r f16(dinv_r) * x_r )

#define GPROC(Q, K, ACC)                                                         \
    {                                                                            \
        unsigned int q_ = (Q);                                                   \
        int idx_ = base + (K);                                                   \
        float vv_ = q2f(sl[(size_t)(q_ & 0xffffu) * ROWB]);                      \
        unsigned int wb_ = (idx_ >= s && idx_ < e) ? (q_ >> 16) : 0u;            \
        ACC += __half2float(__ushort_as_half((unsigned short)wb_)) * vv_;        \
    }

template <bool LSM, typename DstT, int DSTRIDE>
__global__ void k_gather(const int* __restrict__ offs, const unsigned int* __restrict__ csr,
                         const unsigned char* __restrict__ src, const float* __restrict__ dinv,
                         DstT* __restrict__ dst, const float* __restrict__ bias) {
    int wave = threadIdx.x >> 6;
    int lane = threadIdx.x & 63;
    int n = blockIdx.x * 4 + wave;
    if (n >= N_NODES) return;
    int s = offs[n], e = offs[n + 1];
    bool act = (lane < N_CLASSES);
    float dc = dinv[n];
    const unsigned char* sl = src + lane;  // per-lane base; addr = sl + 64*r
    float acc0 = 0.0f, acc1 = 0.0f, acc2 = 0.0f, acc3 = 0.0f;
    if (act) acc0 = dc * q2f(sl[(size_t)n * ROWB]);  // self term (dc applied again at end)
    for (int base = (s & ~15); base < e; base += 16) {
        uint4 q0 = *(const uint4*)(csr + base);
        uint4 q1 = *(const uint4*)(csr + base + 4);
        uint4 q2 = *(const uint4*)(csr + base + 8);
        uint4 q3 = *(const uint4*)(csr + base + 12);
        if (act) {
            GPROC(q0.x,  0, acc0) GPROC(q0.y,  1, acc1) GPROC(q0.z,  2, acc2) GPROC(q0.w,  3, acc3)
            GPROC(q1.x,  4, acc0) GPROC(q1.y,  5, acc1) GPROC(q1.z,  6, acc2) GPROC(q1.w,  7, acc3)
            GPROC(q2.x,  8, acc0) GPROC(q2.y,  9, acc1) GPROC(q2.z, 10, acc2) GPROC(q2.w, 11, acc3)
            GPROC(q3.x, 12, acc0) GPROC(q3.y, 13, acc1) GPROC(q3.z, 14, acc2) GPROC(q3.w, 15, acc3)
        }
    }
    float acc = dc * ((acc0 + acc1) + (acc2 + acc3));
    if (!LSM) {
        if (act) {
            if constexpr (sizeof(DstT) == 1)
                dst[(size_t)n * DSTRIDE + lane] = (DstT)f2q(acc);
            else
                dst[(size_t)n * DSTRIDE + lane] = (DstT)acc;
        }
    } else {
        float v = act ? acc + bias[lane] : -INFINITY;
        float m = v;
#pragma unroll
        for (int off = 32; off; off >>= 1) m = fmaxf(m, __shfl_xor(m, off));
        float ex = act ? __expf(v - m) : 0.0f;
        float ssum = ex;
#pragma unroll
        for (int off = 32; off; off >>= 1) ssum += __shfl_xor(ssum, off);
        float ls = logf(ssum);
        if (act) dst[(size_t)n * DSTRIDE + lane] = (DstT)(v - m - ls);
    }
}

// ---------------- launch ----------------

extern "C" void kernel_launch(void* const* d_in, const int* in_sizes, int n_in,
                              void* d_out, int out_size, void* d_ws, size_t ws_size,
                              hipStream_t stream) {
    const float* x = (const float*)d_in[0];
    const void* ei = d_in[1];                // [2, E], int32 or int64 (wave-local detect)
    const float* W = (const float*)d_in[2];  // [F, C]
    const float* b = (const float*)d_in[3];  // [C]
    float* z = (float*)d_out;                // [N, C]

    // workspace layout (256B-aligned chunks)
    char* ws = (char*)d_ws;
    size_t o = 0;
    auto alloc = [&](size_t bytes) { char* p = ws + o; o += (bytes + 255) & ~(size_t)255; return p; };
    int*            deg    = (int*)alloc(N_NODES * 4);  // 50000 -> 12500 uint4
    unsigned int*   epack  = (unsigned int*)alloc((size_t)N_EDGES * 4);
    float*          dinv   = (float*)alloc(N_NODES * 4);
    unsigned short* dinv16 = (unsigned short*)alloc(N_NODES * 2);
    int*            offs   = (int*)alloc((N_NODES + 1) * 4);
    int*            cursor = (int*)alloc(N_NODES * 4);
    int*            sums   = (int*)alloc(SCAN_BLK * 4);
    unsigned int*   csr    = (unsigned int*)alloc((size_t)(N_EDGES + 16) * 4);
    unsigned char*  y0q    = (unsigned char*)alloc((size_t)N_NODES * ROWB);  // fp8, 64B rows
    unsigned char*  h1q    = (unsigned char*)alloc((size_t)N_NODES * ROWB);  // fp8, 64B rows

    const int T = 256;
    auto blocks = [](long long total, int t) { return (int)((total + t - 1) / t); };

    // zero deg
    k_zero<<<blocks(12500, T), T, 0, stream>>>((uint4*)deg, 12500);

    // convert (dtype ballot + degree count fused)
    k_convert<<<blocks(N_EDGES, T), T, 0, stream>>>(ei, epack, deg);

    // 2-kernel exclusive scan -> offs, cursor (dinv/dinv16 fused; scan2 folded into scan3)
    k_scan1<<<N_SCAN_BLKS, SCAN_BLK, 0, stream>>>(deg, offs, sums, dinv, dinv16);
    k_scan3<<<N_SCAN_BLKS, SCAN_BLK, 0, stream>>>(offs, sums, cursor, csr);

    // fused: XCD-sliced CSR fill + y0q = fp8(x @ W)   (independent work, one launch)
    k_fill_linear<<<FILL_BLOCKS + LIN_BLOCKS, T, 0, stream>>>(epack, dinv16, cursor, csr, x, W, y0q);

    // hop 1: h1q = fp8(A_hat @ y0q)
    k_gather<false, unsigned char, ROWB><<<(N_NODES + 3) / 4, T, 0, stream>>>(offs, csr, y0q, dinv, h1q, b);
    // hop 2 fused with bias + log_softmax: z = log_softmax(A_hat @ h1q + b)
    k_gather<true, float, N_CLASSES><<<(N_NODES + 3) / 4, T, 0, stream>>>(offs, csr, h1q, dinv, z, b);
}